// Round 1
// baseline (348.821 us; speedup 1.0000x reference)
//
#include <hip/hip_runtime.h>
#include <math.h>

// ChannelDropout: out[b,c,t] = x[b,c,t] * scale[b,c]
// scale = (valid && dist(pos, center0) > 0.1) ? 1/(prob_kept + 1e-8) : 0
// prob_kept = mean over centers 1..N-1 of (dist > 0.1)
// valid = !(pos == (-2,-2))
//
// One block per (b,c) row. Wave 0 computes scale (lane-parallel over MC
// centers + shuffle reduce), broadcast via LDS, then all 256 threads stream
// the 3000-float row as float4 (row byte stride 12000 % 16 == 0).

__global__ __launch_bounds__(256) void ChannelDropout_14851996910142_kernel(
    const float* __restrict__ x,
    const float* __restrict__ pos,
    const float* __restrict__ centers,
    float* __restrict__ out,
    int ncenters, int tlen)
{
    const int row = blockIdx.x;
    const int tid = threadIdx.x;
    __shared__ float s_scale;

    if (tid < 64) {
        const float px = pos[2 * row];
        const float py = pos[2 * row + 1];
        const bool valid = !(px == -2.0f && py == -2.0f);

        // Monte-Carlo keep count over centers 1..ncenters-1
        float cnt = 0.0f;
        for (int c = 1 + tid; c < ncenters; c += 64) {
            const float dx = px - centers[2 * c];
            const float dy = py - centers[2 * c + 1];
            // match np: d = sqrt(dx*dx + dy*dy), no fma contraction
            const float d2 = __fadd_rn(__fmul_rn(dx, dx), __fmul_rn(dy, dy));
            const float d = sqrtf(d2);
            cnt += (d > 0.1f) ? 1.0f : 0.0f;
        }
        #pragma unroll
        for (int off = 32; off > 0; off >>= 1)
            cnt += __shfl_down(cnt, off, 64);

        if (tid == 0) {
            const float dx0 = px - centers[0];
            const float dy0 = py - centers[1];
            const float d02 = __fadd_rn(__fmul_rn(dx0, dx0), __fmul_rn(dy0, dy0));
            const bool kept0 = sqrtf(d02) > 0.1f;
            const float prob = cnt / (float)(ncenters - 1);
            s_scale = (valid && kept0) ? (1.0f / (prob + 1e-8f)) : 0.0f;
        }
    }
    __syncthreads();
    const float s = s_scale;

    const size_t base = (size_t)row * (size_t)tlen;
    const int t4 = tlen >> 2;  // 750 float4 per row
    const float4* __restrict__ xr = (const float4*)(x + base);
    float4* __restrict__ orow = (float4*)(out + base);
    for (int i = tid; i < t4; i += 256) {
        float4 v = xr[i];
        v.x *= s; v.y *= s; v.z *= s; v.w *= s;
        orow[i] = v;
    }
    // tail (tlen % 4 != 0) — not taken for tlen = 3000
    for (int i = (t4 << 2) + tid; i < tlen; i += 256) {
        out[base + i] = x[base + i] * s;
    }
}

extern "C" void kernel_launch(void* const* d_in, const int* in_sizes, int n_in,
                              void* d_out, int out_size, void* d_ws, size_t ws_size,
                              hipStream_t stream) {
    const float* x       = (const float*)d_in[0];   // [B, C, T]
    const float* pos     = (const float*)d_in[1];   // [B, C, 2]
    const float* centers = (const float*)d_in[2];   // [N, 2]
    float* out = (float*)d_out;

    const int rows     = in_sizes[1] / 2;       // B*C = 17600
    const int tlen     = in_sizes[0] / rows;    // T = 3000
    const int ncenters = in_sizes[2] / 2;       // 101

    ChannelDropout_14851996910142_kernel<<<rows, 256, 0, stream>>>(
        x, pos, centers, out, ncenters, tlen);
}